// Round 4
// baseline (441.789 us; speedup 1.0000x reference)
//
#include <hip/hip_runtime.h>

// B=16, C=80, layer sizes 128/64/32.
// d_in order: heat0, tl0, br0, heat1, tl1, br1, heat2, tl2, br2.

#define NB 1024      // histogram buckets over score in [0,1)
#define CAP2 2048    // capacity per candidate sub-list (hi / boundary)
#define CHUNK_H 32768   // elements per hist block
#define CHUNK_C 16384   // elements per collect block
#define LCAP 1024       // per-block local candidate buffer (per list)

__device__ __forceinline__ unsigned int ord_f32(float f) {
    unsigned int b = __float_as_uint(f);
    return (b & 0x80000000u) ? ~b : (b | 0x80000000u);
}
__device__ __forceinline__ float unord_f32(unsigned int o) {
    unsigned int b = (o & 0x80000000u) ? (o & 0x7fffffffu) : ~o;
    return __uint_as_float(b);
}
__device__ __forceinline__ int bucket_of(float f) {
    int bi = (int)(f * (float)NB);
    bi = bi < 0 ? 0 : (bi > NB - 1 ? NB - 1 : bi);
    return bi;
}

__device__ __forceinline__ int layer_N(int l)  { return (l == 0) ? 1310720 : (l == 1) ? 327680 : 81920; }
__device__ __forceinline__ int hist_nchunks(int l) { return (l == 0) ? 40 : (l == 1) ? 10 : 3; }
__device__ __forceinline__ int hist_base(int l)    { return (l == 0) ? 0 : (l == 1) ? 640 : 800; }
// total partials: 40*16 + 10*16 + 3*16 = 848

// ---------------- histogram: per-block LDS hist -> private global partial ----------------
__global__ __launch_bounds__(256) void hist_kernel(
    const float* __restrict__ h0, const float* __restrict__ h1, const float* __restrict__ h2,
    int* __restrict__ ph)
{
    int l = blockIdx.z, b = blockIdx.y, chunk = blockIdx.x;
    int nc = hist_nchunks(l);
    if (chunk >= nc) return;
    int N = layer_N(l);
    int elems = min(CHUNK_H, N - chunk * CHUNK_H);
    const float* heat = (l == 0) ? h0 : (l == 1) ? h1 : h2;
    __shared__ int lh[NB];
    for (int i = threadIdx.x; i < NB; i += 256) lh[i] = 0;
    __syncthreads();
    const float4* p = (const float4*)(heat + (size_t)b * N + (size_t)chunk * CHUNK_H);
    int n4 = elems >> 2;
    for (int i = threadIdx.x; i < n4; i += 256) {
        float4 v = p[i];
        atomicAdd(&lh[bucket_of(v.x)], 1);
        atomicAdd(&lh[bucket_of(v.y)], 1);
        atomicAdd(&lh[bucket_of(v.z)], 1);
        atomicAdd(&lh[bucket_of(v.w)], 1);
    }
    __syncthreads();
    int pidx = hist_base(l) + b * nc + chunk;
    int* dst = ph + (size_t)pidx * NB;
    for (int i = threadIdx.x; i < NB; i += 256) dst[i] = lh[i];
}

// ---------------- threshold bucket ----------------
__global__ __launch_bounds__(256) void thresh_kernel(const int* __restrict__ ph,
                                                     int* __restrict__ tb)
{
    int b = blockIdx.x & 15;
    int l = blockIdx.x >> 4;
    int K = (l == 2) ? 1024 : 2000;
    int nc = hist_nchunks(l);
    const int* base = ph + (size_t)(hist_base(l) + b * nc) * NB;
    __shared__ int hh[NB];
    __shared__ int seg[256];
    int s4 = 0;
    for (int j = 0; j < 4; j++) {
        int bkt = threadIdx.x * 4 + j;
        int s = 0;
        for (int c = 0; c < nc; c++) s += base[(size_t)c * NB + bkt];
        hh[bkt] = s;
        s4 += s;
    }
    seg[threadIdx.x] = s4;
    __syncthreads();
    if (threadIdx.x == 0) {
        int acc = 0, si;
        for (si = 255; si >= 0; si--) {
            if (acc + seg[si] >= K) break;
            acc += seg[si];
        }
        if (si < 0) si = 0;  // defensive
        int bidx = si * 4 + 3;
        for (; bidx > si * 4; bidx--) {
            acc += hh[bidx];
            if (acc >= K) break;
        }
        tb[l * 16 + b] = bidx;
    }
}

// ---------------- collection into TWO lists: hi (bucket>t) and boundary (bucket==t) ----------------
__global__ __launch_bounds__(256) void collect_kernel(
    const float* __restrict__ h0, const float* __restrict__ h1, const float* __restrict__ h2,
    const int* __restrict__ tb, int* __restrict__ cnt, unsigned long long* __restrict__ cand)
{
    int l = blockIdx.z, b = blockIdx.y, chunk = blockIdx.x;
    int N = layer_N(l);
    if (chunk * CHUNK_C >= N) return;
    const float* heat = (l == 0) ? h0 : (l == 1) ? h1 : h2;
    int t = tb[l * 16 + b];
    int bl = l * 16 + b;

    __shared__ int lc[2];
    __shared__ int gb[2];
    __shared__ unsigned long long lbuf[2][LCAP];
    if (threadIdx.x < 2) lc[threadIdx.x] = 0;
    __syncthreads();

    const float4* p = (const float4*)(heat + (size_t)b * N + (size_t)chunk * CHUNK_C);
    int base = chunk * CHUNK_C;
    for (int i = threadIdx.x; i < CHUNK_C / 4; i += 256) {
        float4 v = p[i];
        float vs[4] = {v.x, v.y, v.z, v.w};
#pragma unroll
        for (int cc = 0; cc < 4; cc++) {
            int bk = bucket_of(vs[cc]);
            if (bk >= t) {
                int which = (bk > t) ? 0 : 1;
                int pos = atomicAdd(&lc[which], 1);
                if (pos < LCAP) {
                    unsigned int idx = (unsigned int)(base + 4 * i + cc);
                    lbuf[which][pos] = ((unsigned long long)ord_f32(vs[cc]) << 32) | (unsigned int)(~idx);
                }
            }
        }
    }
    __syncthreads();
    if (threadIdx.x < 2) {
        int n = min(lc[threadIdx.x], LCAP);
        gb[threadIdx.x] = atomicAdd(cnt + bl * 2 + threadIdx.x, n);
    }
    __syncthreads();
#pragma unroll
    for (int w = 0; w < 2; w++) {
        int n = min(lc[w], LCAP);
        unsigned long long* cd = cand + ((size_t)bl * 2 + w) * CAP2;
        int g0 = gb[w];
        for (int i = threadIdx.x; i < n; i += 256) {
            int pos = g0 + i;
            if (pos < CAP2) cd[pos] = lbuf[w][i];
        }
    }
}

// ---------------- single-wave in-register bitonic sort of 2048 u64 keys, descending ----------------
__device__ __forceinline__ unsigned long long shfl_xor_u64(unsigned long long a, int j) {
    unsigned int lo = (unsigned int)a, hi = (unsigned int)(a >> 32);
    lo = (unsigned int)__shfl_xor((int)lo, j, 64);
    hi = (unsigned int)__shfl_xor((int)hi, j, 64);
    return ((unsigned long long)hi << 32) | lo;
}

__global__ __launch_bounds__(64) void sort_kernel(const int* __restrict__ cnt,
                                                  unsigned long long* __restrict__ cand)
{
    int idx = blockIdx.x;          // bl*2 + which
    int n = min(cnt[idx], CAP2);
    unsigned long long* src = cand + (size_t)idx * CAP2;
    int lane = threadIdx.x;

    unsigned long long v[32];      // element i = (r<<6) | lane
#pragma unroll
    for (int r = 0; r < 32; r++) {
        int i = (r << 6) | lane;
        v[r] = (i < n) ? src[i] : 0ull;
    }

    for (int k = 2; k <= 2048; k <<= 1) {
        // strides >= 64: partner in same lane (register pair r, r^jr)
        for (int j = k >> 1; j >= 64; j >>= 1) {
            int jr = j >> 6;
#pragma unroll
            for (int r = 0; r < 32; r++) {
                if ((r & jr) == 0) {
                    int rp = r | jr;
                    int i = (r << 6) | lane;
                    unsigned long long a = v[r], bb = v[rp];
                    bool sw = ((i & k) == 0) ? (a < bb) : (a > bb);
                    if (sw) { v[r] = bb; v[rp] = a; }
                }
            }
        }
        // strides < 64: cross-lane via shfl_xor, constant strides for good lowering
#pragma unroll
        for (int js = 32; js >= 1; js >>= 1) {
            if (k > js) {
#pragma unroll
                for (int r = 0; r < 32; r++) {
                    unsigned long long a = v[r];
                    unsigned long long w = shfl_xor_u64(a, js);
                    int i = (r << 6) | lane;
                    bool upper = (lane & js) != 0;
                    bool keep_max = (((i & k) == 0) != upper);
                    bool agw = a > w;
                    v[r] = (keep_max == agw) ? a : w;
                }
            }
        }
    }

#pragma unroll
    for (int r = 0; r < 32; r++) src[(r << 6) | lane] = v[r];
}

// ---------------- build det: concat(hi,bd), validity, stable partition, write rows ----------------
__global__ __launch_bounds__(1024) void build_kernel(
    const float* __restrict__ t0, const float* __restrict__ t1, const float* __restrict__ t2,
    const float* __restrict__ r0, const float* __restrict__ r1, const float* __restrict__ r2,
    const int* __restrict__ cnt, const unsigned long long* __restrict__ cand,
    float* __restrict__ det)
{
    int l = blockIdx.x >> 4;
    int b = blockIdx.x & 15;
    int bl = l * 16 + b;
    int HW = (l == 0) ? 16384 : (l == 1) ? 4096 : 1024;
    int W  = (l == 0) ? 128 : (l == 1) ? 64 : 32;
    int K  = (l == 2) ? 1024 : 2000;
    float scale = (l == 0) ? 8.f : (l == 1) ? 16.f : 32.f;
    const float* tlp = (l == 0) ? t0 : (l == 1) ? t1 : t2;
    const float* brp = (l == 0) ? r0 : (l == 1) ? r1 : r2;

    int n_hi = min(cnt[bl * 2], CAP2);
    const unsigned long long* hi = cand + (size_t)(bl * 2) * CAP2;
    const unsigned long long* bd = cand + (size_t)(bl * 2 + 1) * CAP2;

    __shared__ int wsum[16];
    int tid = threadIdx.x;
    int lane = tid & 63, wid = tid >> 6;

    // each thread handles k = 2*tid, 2*tid+1 (consecutive -> correct scan order)
    float s_[2], bx_[2][4];
    int f_[2];
#pragma unroll
    for (int q = 0; q < 2; q++) {
        int k = 2 * tid + q;
        f_[q] = 0;
        if (k < K) {
            unsigned long long kk = (k < n_hi) ? hi[k] : bd[k - n_hi];
            unsigned int idx = ~(unsigned int)kk;
            float score = unord_f32((unsigned int)(kk >> 32));
            int sp = (int)(idx % (unsigned)HW);
            float xs = (float)(sp % W), ys = (float)(sp / W);
            float tv0 = tlp[((size_t)b * 2 + 0) * HW + sp];
            float tv1 = tlp[((size_t)b * 2 + 1) * HW + sp];
            float bv0 = brp[((size_t)b * 2 + 0) * HW + sp];
            float bv1 = brp[((size_t)b * 2 + 1) * HW + sp];
            float tlx = __fsub_rn(xs, __fadd_rn(__fmul_rn(1.5f, tv0), 2.25f));
            float tly = __fsub_rn(ys, __fadd_rn(__fmul_rn(1.5f, tv1), 2.25f));
            float brx = __fadd_rn(xs, __fadd_rn(__fmul_rn(1.5f, bv0), 2.25f));
            float bry = __fadd_rn(ys, __fadd_rn(__fmul_rn(1.5f, bv1), 2.25f));
            bool invalid = (brx < tlx) || (bry < tly);
            f_[q] = invalid ? 0 : 1;
            s_[q] = invalid ? -1.0f : score;
            bx_[q][0] = __fmul_rn(tlx, scale);
            bx_[q][1] = __fmul_rn(tly, scale);
            bx_[q][2] = __fmul_rn(brx, scale);
            bx_[q][3] = __fmul_rn(bry, scale);
        }
    }
    int mysum = f_[0] + f_[1];

    // wave-level inclusive scan of mysum
    int x = mysum;
#pragma unroll
    for (int off = 1; off < 64; off <<= 1) {
        int y = __shfl_up(x, off, 64);
        if (lane >= off) x += y;
    }
    if (lane == 63) wsum[wid] = x;
    __syncthreads();
    if (wid == 0 && lane < 16) {
        int s = wsum[lane];
#pragma unroll
        for (int off = 1; off < 16; off <<= 1) {
            int y = __shfl_up(s, off, 64);
            if (lane >= off) s += y;
        }
        wsum[lane] = s;   // inclusive per-wave prefix
    }
    __syncthreads();
    int wave_off = (wid > 0) ? wsum[wid - 1] : 0;
    int V = wsum[15];
    int base_excl = (x + wave_off) - mysum;   // # valid strictly before element 2*tid

    float* dbase = det + ((size_t)b * 3000 + (size_t)l * 1000) * 7;
#pragma unroll
    for (int q = 0; q < 2; q++) {
        int k = 2 * tid + q;
        if (k < K) {
            int pos = base_excl + (q == 1 ? f_[0] : 0);   // # valid before k
            int rank = f_[q] ? pos : V + (k - pos);
            if (rank < 1000 && rank != 6) {
                float* drow = dbase + (size_t)rank * 7;
                drow[0] = s_[q];
                drow[1] = bx_[q][0];
                drow[2] = bx_[q][1];
                drow[3] = bx_[q][2];
                drow[4] = bx_[q][3];
                drow[5] = 0.f;
                drow[6] = 0.f;
            }
        }
    }
    if (tid == 0) {
        float lv = (float)l;
        float* drow = dbase + 6 * 7;
#pragma unroll
        for (int j = 0; j < 7; j++) drow[j] = lv;
    }
}

// ---------------- final: merge-rank of 3 sorted lists (+3 clobbered singletons) ----------------
__device__ __forceinline__ bool key_gt(float sa, int ga, float sb, int gb) {
    return (sa > sb) || (sa == sb && ga < gb);
}

__global__ __launch_bounds__(1024) void final_kernel(const float* __restrict__ det,
                                                     float* __restrict__ out)
{
    int b = blockIdx.x;
    __shared__ float sc[3000];
    int tid = threadIdx.x;
    const float* dbase = det + (size_t)b * 3000 * 7;
    for (int i = tid; i < 3000; i += 1024) sc[i] = dbase[(size_t)i * 7];
    __syncthreads();

    for (int e = tid; e < 3000; e += 1024) {
        float se = sc[e];
        int ge = e;
        int rank = 0;
#pragma unroll
        for (int lp = 0; lp < 3; lp++) {
            int lo = 0, hiB = 999;
            while (lo < hiB) {
                int mid = (lo + hiB) >> 1;
                int p = mid + (mid >= 6 ? 1 : 0);
                int g = lp * 1000 + p;
                if (key_gt(sc[g], g, se, ge)) lo = mid + 1; else hiB = mid;
            }
            rank += lo;
        }
#pragma unroll
        for (int ls = 0; ls < 3; ls++) {
            int g = ls * 1000 + 6;
            if (g != e && key_gt((float)ls, g, se, ge)) rank++;
        }
        if (rank < 1000) {
            const float* src = dbase + (size_t)e * 7;
            float* dst = out + ((size_t)b * 1000 + rank) * 7;
#pragma unroll
            for (int j = 0; j < 7; j++) dst[j] = src[j];
        }
    }
}

extern "C" void kernel_launch(void* const* d_in, const int* in_sizes, int n_in,
                              void* d_out, int out_size, void* d_ws, size_t ws_size,
                              hipStream_t stream)
{
    (void)in_sizes; (void)n_in; (void)out_size; (void)ws_size;
    const float* h0 = (const float*)d_in[0];
    const float* t0 = (const float*)d_in[1];
    const float* r0 = (const float*)d_in[2];
    const float* h1 = (const float*)d_in[3];
    const float* t1 = (const float*)d_in[4];
    const float* r1 = (const float*)d_in[5];
    const float* h2 = (const float*)d_in[6];
    const float* t2 = (const float*)d_in[7];
    const float* r2 = (const float*)d_in[8];
    float* out = (float*)d_out;

    // Workspace layout (bytes):
    //   ph  : 848*1024*4 = 3473408   @ 0
    //   cnt : 96*4       = 384       @ 3473408  (memset 0)
    //   tb  : 48*4       = 192       @ 3473792
    //   cand: 96*2048*8  = 1572864   @ 3473984  (8B aligned)
    //   det : 16*3000*7*4= 1344000   @ 5046848
    char* ws = (char*)d_ws;
    int* ph   = (int*)ws;
    int* cnt  = (int*)(ws + 3473408);
    int* tb   = (int*)(ws + 3473792);
    unsigned long long* cand = (unsigned long long*)(ws + 3473984);
    float* det = (float*)(ws + 5046848);

    hipMemsetAsync(cnt, 0, 384, stream);

    hist_kernel<<<dim3(40, 16, 3), 256, 0, stream>>>(h0, h1, h2, ph);
    thresh_kernel<<<48, 256, 0, stream>>>(ph, tb);
    collect_kernel<<<dim3(80, 16, 3), 256, 0, stream>>>(h0, h1, h2, tb, cnt, cand);
    sort_kernel<<<96, 64, 0, stream>>>(cnt, cand);
    build_kernel<<<48, 1024, 0, stream>>>(t0, t1, t2, r0, r1, r2, cnt, cand, det);
    final_kernel<<<16, 1024, 0, stream>>>(det, out);
}

// Round 5
// 300.665 us; speedup vs baseline: 1.4694x; 1.4694x over previous
//
#include <hip/hip_runtime.h>

// B=16, C=80, layer sizes 128/64/32.
// d_in order: heat0, tl0, br0, heat1, tl1, br1, heat2, tl2, br2.

#define NB 1024      // histogram buckets over score in [0,1)
#define CAP2 2048    // capacity per candidate sub-list (hi / boundary)
#define CHUNK_H 32768   // elements per hist block
#define CHUNK_C 16384   // elements per collect block
#define LCAP 1024       // per-block local candidate buffer (per list)

__device__ __forceinline__ unsigned int ord_f32(float f) {
    unsigned int b = __float_as_uint(f);
    return (b & 0x80000000u) ? ~b : (b | 0x80000000u);
}
__device__ __forceinline__ float unord_f32(unsigned int o) {
    unsigned int b = (o & 0x80000000u) ? (o & 0x7fffffffu) : ~o;
    return __uint_as_float(b);
}
__device__ __forceinline__ int bucket_of(float f) {
    int bi = (int)(f * (float)NB);
    bi = bi < 0 ? 0 : (bi > NB - 1 ? NB - 1 : bi);
    return bi;
}

__device__ __forceinline__ int layer_N(int l)  { return (l == 0) ? 1310720 : (l == 1) ? 327680 : 81920; }
__device__ __forceinline__ int hist_nchunks(int l) { return (l == 0) ? 40 : (l == 1) ? 10 : 3; }
__device__ __forceinline__ int hist_base(int l)    { return (l == 0) ? 0 : (l == 1) ? 640 : 800; }
// total partials: 40*16 + 10*16 + 3*16 = 848

// ---------------- histogram: per-block LDS hist -> private global partial ----------------
__global__ __launch_bounds__(256) void hist_kernel(
    const float* __restrict__ h0, const float* __restrict__ h1, const float* __restrict__ h2,
    int* __restrict__ ph)
{
    int l = blockIdx.z, b = blockIdx.y, chunk = blockIdx.x;
    int nc = hist_nchunks(l);
    if (chunk >= nc) return;
    int N = layer_N(l);
    int elems = min(CHUNK_H, N - chunk * CHUNK_H);
    const float* heat = (l == 0) ? h0 : (l == 1) ? h1 : h2;
    __shared__ int lh[NB];
    for (int i = threadIdx.x; i < NB; i += 256) lh[i] = 0;
    __syncthreads();
    const float4* p = (const float4*)(heat + (size_t)b * N + (size_t)chunk * CHUNK_H);
    int n4 = elems >> 2;
    for (int i = threadIdx.x; i < n4; i += 256) {
        float4 v = p[i];
        atomicAdd(&lh[bucket_of(v.x)], 1);
        atomicAdd(&lh[bucket_of(v.y)], 1);
        atomicAdd(&lh[bucket_of(v.z)], 1);
        atomicAdd(&lh[bucket_of(v.w)], 1);
    }
    __syncthreads();
    int pidx = hist_base(l) + b * nc + chunk;
    int* dst = ph + (size_t)pidx * NB;
    for (int i = threadIdx.x; i < NB; i += 256) dst[i] = lh[i];
}

// ---------------- threshold bucket ----------------
__global__ __launch_bounds__(256) void thresh_kernel(const int* __restrict__ ph,
                                                     int* __restrict__ tb)
{
    int b = blockIdx.x & 15;
    int l = blockIdx.x >> 4;
    int K = (l == 2) ? 1024 : 2000;
    int nc = hist_nchunks(l);
    const int* base = ph + (size_t)(hist_base(l) + b * nc) * NB;
    __shared__ int hh[NB];
    __shared__ int seg[256];
    int s4 = 0;
    for (int j = 0; j < 4; j++) {
        int bkt = threadIdx.x * 4 + j;
        int s = 0;
        for (int c = 0; c < nc; c++) s += base[(size_t)c * NB + bkt];
        hh[bkt] = s;
        s4 += s;
    }
    seg[threadIdx.x] = s4;
    __syncthreads();
    if (threadIdx.x == 0) {
        int acc = 0, si;
        for (si = 255; si >= 0; si--) {
            if (acc + seg[si] >= K) break;
            acc += seg[si];
        }
        if (si < 0) si = 0;  // defensive
        int bidx = si * 4 + 3;
        for (; bidx > si * 4; bidx--) {
            acc += hh[bidx];
            if (acc >= K) break;
        }
        tb[l * 16 + b] = bidx;
    }
}

// ---------------- collection into TWO lists: hi (bucket>t) and boundary (bucket==t) ----------------
__global__ __launch_bounds__(256) void collect_kernel(
    const float* __restrict__ h0, const float* __restrict__ h1, const float* __restrict__ h2,
    const int* __restrict__ tb, int* __restrict__ cnt, unsigned long long* __restrict__ cand)
{
    int l = blockIdx.z, b = blockIdx.y, chunk = blockIdx.x;
    int N = layer_N(l);
    if (chunk * CHUNK_C >= N) return;
    const float* heat = (l == 0) ? h0 : (l == 1) ? h1 : h2;
    int t = tb[l * 16 + b];
    int bl = l * 16 + b;

    __shared__ int lc[2];
    __shared__ int gb[2];
    __shared__ unsigned long long lbuf[2][LCAP];
    if (threadIdx.x < 2) lc[threadIdx.x] = 0;
    __syncthreads();

    const float4* p = (const float4*)(heat + (size_t)b * N + (size_t)chunk * CHUNK_C);
    int base = chunk * CHUNK_C;
    for (int i = threadIdx.x; i < CHUNK_C / 4; i += 256) {
        float4 v = p[i];
        float vs[4] = {v.x, v.y, v.z, v.w};
#pragma unroll
        for (int cc = 0; cc < 4; cc++) {
            int bk = bucket_of(vs[cc]);
            if (bk >= t) {
                int which = (bk > t) ? 0 : 1;
                int pos = atomicAdd(&lc[which], 1);
                if (pos < LCAP) {
                    unsigned int idx = (unsigned int)(base + 4 * i + cc);
                    lbuf[which][pos] = ((unsigned long long)ord_f32(vs[cc]) << 32) | (unsigned int)(~idx);
                }
            }
        }
    }
    __syncthreads();
    if (threadIdx.x < 2) {
        int n = min(lc[threadIdx.x], LCAP);
        gb[threadIdx.x] = atomicAdd(cnt + bl * 2 + threadIdx.x, n);
    }
    __syncthreads();
#pragma unroll
    for (int w = 0; w < 2; w++) {
        int n = min(lc[w], LCAP);
        unsigned long long* cd = cand + ((size_t)bl * 2 + w) * CAP2;
        int g0 = gb[w];
        for (int i = threadIdx.x; i < n; i += 256) {
            int pos = g0 + i;
            if (pos < CAP2) cd[pos] = lbuf[w][i];
        }
    }
}

// ---------------- single-wave in-register bitonic sort, FULLY STATIC indices ----------------
// element i = (r<<6) | lane; r in [0,32), lane in [0,64). All register indices are
// compile-time constants via template recursion (R4's runtime k-loop demoted v[] to
// scratch: VGPR_Count=80, 204us. This version keeps v[] in 64 VGPRs.)

__device__ __forceinline__ unsigned long long shfl_xor_u64(unsigned long long a, int j) {
    unsigned int lo = (unsigned int)a, hi = (unsigned int)(a >> 32);
    lo = (unsigned int)__shfl_xor((int)lo, j, 64);
    hi = (unsigned int)__shfl_xor((int)hi, j, 64);
    return ((unsigned long long)hi << 32) | lo;
}

template<int K, int J>
struct Phase {
    static __device__ __forceinline__ void run(unsigned long long (&v)[32], int lane) {
        constexpr int JR = J >> 6;   // J >= 64 here
#pragma unroll
        for (int r = 0; r < 32; r++) {
            if ((r & JR) == 0) {
                int i = (r << 6) | lane;
                unsigned long long a = v[r], bb = v[r | JR];
                bool sw = ((i & K) == 0) ? (a < bb) : (a > bb);
                if (sw) { v[r] = bb; v[r | JR] = a; }
            }
        }
        Phase<K, (J >> 1)>::run(v, lane);
    }
};

// J == 32 terminator: all cross-lane strides 32..1 via shfl_xor (constexpr-guarded)
template<int K>
struct Phase<K, 32> {
    static __device__ __forceinline__ void run(unsigned long long (&v)[32], int lane) {
#pragma unroll
        for (int js = 32; js >= 1; js >>= 1) {
            if (K > js) {
#pragma unroll
                for (int r = 0; r < 32; r++) {
                    unsigned long long a = v[r];
                    unsigned long long w = shfl_xor_u64(a, js);
                    int i = (r << 6) | lane;
                    bool upper = (lane & js) != 0;
                    bool keep_max = (((i & K) == 0) != upper);
                    bool agw = a > w;
                    v[r] = (keep_max == agw) ? a : w;
                }
            }
        }
    }
};

template<int K>
struct Stage {
    static __device__ __forceinline__ void run(unsigned long long (&v)[32], int lane) {
        Phase<K, (K > 64 ? (K >> 1) : 32)>::run(v, lane);
        Stage<(K << 1)>::run(v, lane);
    }
};
template<>
struct Stage<4096> {
    static __device__ __forceinline__ void run(unsigned long long (&)[32], int) {}
};

__global__ __launch_bounds__(64) void sort_kernel(const int* __restrict__ cnt,
                                                  unsigned long long* __restrict__ cand)
{
    int idx = blockIdx.x;          // bl*2 + which
    int n = min(cnt[idx], CAP2);
    unsigned long long* src = cand + (size_t)idx * CAP2;
    int lane = threadIdx.x;

    unsigned long long v[32];      // element i = (r<<6) | lane  -> 64 VGPRs
#pragma unroll
    for (int r = 0; r < 32; r++) {
        int i = (r << 6) | lane;
        v[r] = (i < n) ? src[i] : 0ull;
    }

    Stage<2>::run(v, lane);

#pragma unroll
    for (int r = 0; r < 32; r++) src[(r << 6) | lane] = v[r];
}

// ---------------- build det: concat(hi,bd), validity, stable partition, write rows ----------------
__global__ __launch_bounds__(1024) void build_kernel(
    const float* __restrict__ t0, const float* __restrict__ t1, const float* __restrict__ t2,
    const float* __restrict__ r0, const float* __restrict__ r1, const float* __restrict__ r2,
    const int* __restrict__ cnt, const unsigned long long* __restrict__ cand,
    float* __restrict__ det)
{
    int l = blockIdx.x >> 4;
    int b = blockIdx.x & 15;
    int bl = l * 16 + b;
    int HW = (l == 0) ? 16384 : (l == 1) ? 4096 : 1024;
    int W  = (l == 0) ? 128 : (l == 1) ? 64 : 32;
    int K  = (l == 2) ? 1024 : 2000;
    float scale = (l == 0) ? 8.f : (l == 1) ? 16.f : 32.f;
    const float* tlp = (l == 0) ? t0 : (l == 1) ? t1 : t2;
    const float* brp = (l == 0) ? r0 : (l == 1) ? r1 : r2;

    int n_hi = min(cnt[bl * 2], CAP2);
    const unsigned long long* hi = cand + (size_t)(bl * 2) * CAP2;
    const unsigned long long* bd = cand + (size_t)(bl * 2 + 1) * CAP2;

    __shared__ int wsum[16];
    int tid = threadIdx.x;
    int lane = tid & 63, wid = tid >> 6;

    // each thread handles k = 2*tid, 2*tid+1 (consecutive -> correct scan order)
    float s_[2], bx_[2][4];
    int f_[2];
#pragma unroll
    for (int q = 0; q < 2; q++) {
        int k = 2 * tid + q;
        f_[q] = 0;
        if (k < K) {
            unsigned long long kk = (k < n_hi) ? hi[k] : bd[k - n_hi];
            unsigned int idx = ~(unsigned int)kk;
            float score = unord_f32((unsigned int)(kk >> 32));
            int sp = (int)(idx % (unsigned)HW);
            float xs = (float)(sp % W), ys = (float)(sp / W);
            float tv0 = tlp[((size_t)b * 2 + 0) * HW + sp];
            float tv1 = tlp[((size_t)b * 2 + 1) * HW + sp];
            float bv0 = brp[((size_t)b * 2 + 0) * HW + sp];
            float bv1 = brp[((size_t)b * 2 + 1) * HW + sp];
            float tlx = __fsub_rn(xs, __fadd_rn(__fmul_rn(1.5f, tv0), 2.25f));
            float tly = __fsub_rn(ys, __fadd_rn(__fmul_rn(1.5f, tv1), 2.25f));
            float brx = __fadd_rn(xs, __fadd_rn(__fmul_rn(1.5f, bv0), 2.25f));
            float bry = __fadd_rn(ys, __fadd_rn(__fmul_rn(1.5f, bv1), 2.25f));
            bool invalid = (brx < tlx) || (bry < tly);
            f_[q] = invalid ? 0 : 1;
            s_[q] = invalid ? -1.0f : score;
            bx_[q][0] = __fmul_rn(tlx, scale);
            bx_[q][1] = __fmul_rn(tly, scale);
            bx_[q][2] = __fmul_rn(brx, scale);
            bx_[q][3] = __fmul_rn(bry, scale);
        }
    }
    int mysum = f_[0] + f_[1];

    // wave-level inclusive scan of mysum
    int x = mysum;
#pragma unroll
    for (int off = 1; off < 64; off <<= 1) {
        int y = __shfl_up(x, off, 64);
        if (lane >= off) x += y;
    }
    if (lane == 63) wsum[wid] = x;
    __syncthreads();
    if (wid == 0 && lane < 16) {
        int s = wsum[lane];
#pragma unroll
        for (int off = 1; off < 16; off <<= 1) {
            int y = __shfl_up(s, off, 64);
            if (lane >= off) s += y;
        }
        wsum[lane] = s;   // inclusive per-wave prefix
    }
    __syncthreads();
    int wave_off = (wid > 0) ? wsum[wid - 1] : 0;
    int V = wsum[15];
    int base_excl = (x + wave_off) - mysum;   // # valid strictly before element 2*tid

    float* dbase = det + ((size_t)b * 3000 + (size_t)l * 1000) * 7;
#pragma unroll
    for (int q = 0; q < 2; q++) {
        int k = 2 * tid + q;
        if (k < K) {
            int pos = base_excl + (q == 1 ? f_[0] : 0);   // # valid before k
            int rank = f_[q] ? pos : V + (k - pos);
            if (rank < 1000 && rank != 6) {
                float* drow = dbase + (size_t)rank * 7;
                drow[0] = s_[q];
                drow[1] = bx_[q][0];
                drow[2] = bx_[q][1];
                drow[3] = bx_[q][2];
                drow[4] = bx_[q][3];
                drow[5] = 0.f;
                drow[6] = 0.f;
            }
        }
    }
    if (tid == 0) {
        float lv = (float)l;
        float* drow = dbase + 6 * 7;
#pragma unroll
        for (int j = 0; j < 7; j++) drow[j] = lv;
    }
}

// ---------------- final: merge-rank of 3 sorted lists (+3 clobbered singletons) ----------------
__device__ __forceinline__ bool key_gt(float sa, int ga, float sb, int gb) {
    return (sa > sb) || (sa == sb && ga < gb);
}

__global__ __launch_bounds__(1024) void final_kernel(const float* __restrict__ det,
                                                     float* __restrict__ out)
{
    int b = blockIdx.x;
    __shared__ float sc[3000];
    int tid = threadIdx.x;
    const float* dbase = det + (size_t)b * 3000 * 7;
    for (int i = tid; i < 3000; i += 1024) sc[i] = dbase[(size_t)i * 7];
    __syncthreads();

    for (int e = tid; e < 3000; e += 1024) {
        float se = sc[e];
        int ge = e;
        int rank = 0;
#pragma unroll
        for (int lp = 0; lp < 3; lp++) {
            int lo = 0, hiB = 999;
            while (lo < hiB) {
                int mid = (lo + hiB) >> 1;
                int p = mid + (mid >= 6 ? 1 : 0);
                int g = lp * 1000 + p;
                if (key_gt(sc[g], g, se, ge)) lo = mid + 1; else hiB = mid;
            }
            rank += lo;
        }
#pragma unroll
        for (int ls = 0; ls < 3; ls++) {
            int g = ls * 1000 + 6;
            if (g != e && key_gt((float)ls, g, se, ge)) rank++;
        }
        if (rank < 1000) {
            const float* src = dbase + (size_t)e * 7;
            float* dst = out + ((size_t)b * 1000 + rank) * 7;
#pragma unroll
            for (int j = 0; j < 7; j++) dst[j] = src[j];
        }
    }
}

extern "C" void kernel_launch(void* const* d_in, const int* in_sizes, int n_in,
                              void* d_out, int out_size, void* d_ws, size_t ws_size,
                              hipStream_t stream)
{
    (void)in_sizes; (void)n_in; (void)out_size; (void)ws_size;
    const float* h0 = (const float*)d_in[0];
    const float* t0 = (const float*)d_in[1];
    const float* r0 = (const float*)d_in[2];
    const float* h1 = (const float*)d_in[3];
    const float* t1 = (const float*)d_in[4];
    const float* r1 = (const float*)d_in[5];
    const float* h2 = (const float*)d_in[6];
    const float* t2 = (const float*)d_in[7];
    const float* r2 = (const float*)d_in[8];
    float* out = (float*)d_out;

    // Workspace layout (bytes):
    //   ph  : 848*1024*4 = 3473408   @ 0
    //   cnt : 96*4       = 384       @ 3473408  (memset 0)
    //   tb  : 48*4       = 192       @ 3473792
    //   cand: 96*2048*8  = 1572864   @ 3473984  (8B aligned)
    //   det : 16*3000*7*4= 1344000   @ 5046848
    char* ws = (char*)d_ws;
    int* ph   = (int*)ws;
    int* cnt  = (int*)(ws + 3473408);
    int* tb   = (int*)(ws + 3473792);
    unsigned long long* cand = (unsigned long long*)(ws + 3473984);
    float* det = (float*)(ws + 5046848);

    hipMemsetAsync(cnt, 0, 384, stream);

    hist_kernel<<<dim3(40, 16, 3), 256, 0, stream>>>(h0, h1, h2, ph);
    thresh_kernel<<<48, 256, 0, stream>>>(ph, tb);
    collect_kernel<<<dim3(80, 16, 3), 256, 0, stream>>>(h0, h1, h2, tb, cnt, cand);
    sort_kernel<<<96, 64, 0, stream>>>(cnt, cand);
    build_kernel<<<48, 1024, 0, stream>>>(t0, t1, t2, r0, r1, r2, cnt, cand, det);
    final_kernel<<<16, 1024, 0, stream>>>(det, out);
}

// Round 6
// 256.828 us; speedup vs baseline: 1.7202x; 1.1707x over previous
//
#include <hip/hip_runtime.h>

// B=16, C=80, layer sizes 128/64/32.
// d_in order: heat0, tl0, br0, heat1, tl1, br1, heat2, tl2, br2.

#define NB 1024      // histogram buckets over score in [0,1)
#define CAP2 2048    // capacity per candidate sub-list (hi / boundary)
#define CHUNK_H 32768   // elements per hist block
#define CHUNK_C 16384   // elements per collect block
#define LCAP 1024       // per-block local candidate buffer (per list)

__device__ __forceinline__ unsigned int ord_f32(float f) {
    unsigned int b = __float_as_uint(f);
    return (b & 0x80000000u) ? ~b : (b | 0x80000000u);
}
__device__ __forceinline__ float unord_f32(unsigned int o) {
    unsigned int b = (o & 0x80000000u) ? (o & 0x7fffffffu) : ~o;
    return __uint_as_float(b);
}
__device__ __forceinline__ int bucket_of(float f) {
    int bi = (int)(f * (float)NB);
    bi = bi < 0 ? 0 : (bi > NB - 1 ? NB - 1 : bi);
    return bi;
}

__device__ __forceinline__ int layer_N(int l)  { return (l == 0) ? 1310720 : (l == 1) ? 327680 : 81920; }
__device__ __forceinline__ int hist_nchunks(int l) { return (l == 0) ? 40 : (l == 1) ? 10 : 3; }
__device__ __forceinline__ int hist_base(int l)    { return (l == 0) ? 0 : (l == 1) ? 640 : 800; }
// total partials: 40*16 + 10*16 + 3*16 = 848

// ---------------- histogram: per-block LDS hist -> private global partial ----------------
__global__ __launch_bounds__(256) void hist_kernel(
    const float* __restrict__ h0, const float* __restrict__ h1, const float* __restrict__ h2,
    int* __restrict__ ph)
{
    int l = blockIdx.z, b = blockIdx.y, chunk = blockIdx.x;
    int nc = hist_nchunks(l);
    if (chunk >= nc) return;
    int N = layer_N(l);
    int elems = min(CHUNK_H, N - chunk * CHUNK_H);
    const float* heat = (l == 0) ? h0 : (l == 1) ? h1 : h2;
    __shared__ int lh[NB];
    for (int i = threadIdx.x; i < NB; i += 256) lh[i] = 0;
    __syncthreads();
    const float4* p = (const float4*)(heat + (size_t)b * N + (size_t)chunk * CHUNK_H);
    int n4 = elems >> 2;
    for (int i = threadIdx.x; i < n4; i += 256) {
        float4 v = p[i];
        atomicAdd(&lh[bucket_of(v.x)], 1);
        atomicAdd(&lh[bucket_of(v.y)], 1);
        atomicAdd(&lh[bucket_of(v.z)], 1);
        atomicAdd(&lh[bucket_of(v.w)], 1);
    }
    __syncthreads();
    int pidx = hist_base(l) + b * nc + chunk;
    int* dst = ph + (size_t)pidx * NB;
    for (int i = threadIdx.x; i < NB; i += 256) dst[i] = lh[i];
}

// ---------------- threshold bucket (also zeroes cnt for collect) ----------------
__global__ __launch_bounds__(256) void thresh_kernel(const int* __restrict__ ph,
                                                     int* __restrict__ tb,
                                                     int* __restrict__ cnt)
{
    int b = blockIdx.x & 15;
    int l = blockIdx.x >> 4;
    int bl = l * 16 + b;
    if (threadIdx.x < 2) cnt[bl * 2 + threadIdx.x] = 0;
    int K = (l == 2) ? 1024 : 2000;
    int nc = hist_nchunks(l);
    const int* base = ph + (size_t)(hist_base(l) + b * nc) * NB;
    __shared__ int hh[NB];
    __shared__ int seg[256];
    int s4 = 0;
    for (int j = 0; j < 4; j++) {
        int bkt = threadIdx.x * 4 + j;
        int s = 0;
        for (int c = 0; c < nc; c++) s += base[(size_t)c * NB + bkt];
        hh[bkt] = s;
        s4 += s;
    }
    seg[threadIdx.x] = s4;
    __syncthreads();
    if (threadIdx.x == 0) {
        int acc = 0, si;
        for (si = 255; si >= 0; si--) {
            if (acc + seg[si] >= K) break;
            acc += seg[si];
        }
        if (si < 0) si = 0;  // defensive
        int bidx = si * 4 + 3;
        for (; bidx > si * 4; bidx--) {
            acc += hh[bidx];
            if (acc >= K) break;
        }
        tb[bl] = bidx;
    }
}

// ---------------- collection into TWO lists: hi (bucket>t) and boundary (bucket==t) ----------------
__global__ __launch_bounds__(256) void collect_kernel(
    const float* __restrict__ h0, const float* __restrict__ h1, const float* __restrict__ h2,
    const int* __restrict__ tb, int* __restrict__ cnt, unsigned long long* __restrict__ cand)
{
    int l = blockIdx.z, b = blockIdx.y, chunk = blockIdx.x;
    int N = layer_N(l);
    if (chunk * CHUNK_C >= N) return;
    const float* heat = (l == 0) ? h0 : (l == 1) ? h1 : h2;
    int t = tb[l * 16 + b];
    int bl = l * 16 + b;

    __shared__ int lc[2];
    __shared__ int gb[2];
    __shared__ unsigned long long lbuf[2][LCAP];
    if (threadIdx.x < 2) lc[threadIdx.x] = 0;
    __syncthreads();

    const float4* p = (const float4*)(heat + (size_t)b * N + (size_t)chunk * CHUNK_C);
    int base = chunk * CHUNK_C;
    for (int i = threadIdx.x; i < CHUNK_C / 4; i += 256) {
        float4 v = p[i];
        float vs[4] = {v.x, v.y, v.z, v.w};
#pragma unroll
        for (int cc = 0; cc < 4; cc++) {
            int bk = bucket_of(vs[cc]);
            if (bk >= t) {
                int which = (bk > t) ? 0 : 1;
                int pos = atomicAdd(&lc[which], 1);
                if (pos < LCAP) {
                    unsigned int idx = (unsigned int)(base + 4 * i + cc);
                    lbuf[which][pos] = ((unsigned long long)ord_f32(vs[cc]) << 32) | (unsigned int)(~idx);
                }
            }
        }
    }
    __syncthreads();
    if (threadIdx.x < 2) {
        int n = min(lc[threadIdx.x], LCAP);
        gb[threadIdx.x] = atomicAdd(cnt + bl * 2 + threadIdx.x, n);
    }
    __syncthreads();
#pragma unroll
    for (int w = 0; w < 2; w++) {
        int n = min(lc[w], LCAP);
        unsigned long long* cd = cand + ((size_t)bl * 2 + w) * CAP2;
        int g0 = gb[w];
        for (int i = threadIdx.x; i < n; i += 256) {
            int pos = g0 + i;
            if (pos < CAP2) cd[pos] = lbuf[w][i];
        }
    }
}

// ---------------- 4-wave hybrid bitonic sort of 2048 u64 keys, descending ----------------
// Each wave owns 512 elements: i = (wid<<9) | (r<<6) | lane, r in [0,8).
// Stages K=2..512: barrier-free (register pairs for strides 64..256, shfl_xor <64).
// Stages K=1024/2048: 3 LDS exchanges (~6 barriers) + barrier-free local strides.
// (R4: runtime indices -> scratch, 204us. R5: 1 wave/list -> DS-issue bound, 59us.)

__device__ __forceinline__ unsigned long long shfl_xor_u64(unsigned long long a, int j) {
    unsigned int lo = (unsigned int)a, hi = (unsigned int)(a >> 32);
    lo = (unsigned int)__shfl_xor((int)lo, j, 64);
    hi = (unsigned int)__shfl_xor((int)hi, j, 64);
    return ((unsigned long long)hi << 32) | lo;
}

template<int K, int J>
struct PhaseH {
    static __device__ __forceinline__ void run(unsigned long long (&v)[8], int base, int lane) {
        constexpr int JR = J >> 6;   // 64 <= J <= 256 here -> JR in {1,2,4}
#pragma unroll
        for (int r = 0; r < 8; r++) {
            if ((r & JR) == 0) {
                int i = base | (r << 6) | lane;
                unsigned long long a = v[r], bb = v[r | JR];
                bool sw = ((i & K) == 0) ? (a < bb) : (a > bb);
                if (sw) { v[r] = bb; v[r | JR] = a; }
            }
        }
        PhaseH<K, (J >> 1)>::run(v, base, lane);
    }
};

// J == 32 terminator: cross-lane strides 32..1 via shfl_xor (constexpr-guarded)
template<int K>
struct PhaseH<K, 32> {
    static __device__ __forceinline__ void run(unsigned long long (&v)[8], int base, int lane) {
#pragma unroll
        for (int js = 32; js >= 1; js >>= 1) {
            if (K > js) {
#pragma unroll
                for (int r = 0; r < 8; r++) {
                    unsigned long long a = v[r];
                    unsigned long long w = shfl_xor_u64(a, js);
                    int i = base | (r << 6) | lane;
                    bool upper = (lane & js) != 0;
                    bool keep_max = (((i & K) == 0) != upper);
                    bool agw = a > w;
                    v[r] = (keep_max == agw) ? a : w;
                }
            }
        }
    }
};

template<int K>
struct StageH {
    static __device__ __forceinline__ void run(unsigned long long (&v)[8], int base, int lane) {
        PhaseH<K, (K > 64 ? (K >> 1) : 32)>::run(v, base, lane);
        StageH<(K << 1)>::run(v, base, lane);
    }
};
template<>
struct StageH<1024> {
    static __device__ __forceinline__ void run(unsigned long long (&)[8], int, int) {}
};

template<int K, int J>
__device__ __forceinline__ void lds_exchange(unsigned long long (&v)[8],
                                             unsigned long long* lds, int base, int lane) {
    __syncthreads();   // protect any previous LDS reads
#pragma unroll
    for (int r = 0; r < 8; r++) lds[base | (r << 6) | lane] = v[r];
    __syncthreads();
#pragma unroll
    for (int r = 0; r < 8; r++) {
        int i = base | (r << 6) | lane;
        unsigned long long w = lds[i ^ J];
        bool upper = (i & J) != 0;
        bool keep_max = (((i & K) == 0) != upper);
        bool agw = v[r] > w;
        v[r] = (keep_max == agw) ? v[r] : w;
    }
}

__global__ __launch_bounds__(256) void sort_kernel(const int* __restrict__ cnt,
                                                   unsigned long long* __restrict__ cand)
{
    int idx = blockIdx.x;          // bl*2 + which
    int n = min(cnt[idx], CAP2);
    unsigned long long* src = cand + (size_t)idx * CAP2;
    __shared__ unsigned long long lds[CAP2];
    int tid = threadIdx.x;
    int lane = tid & 63;
    int base = (tid >> 6) << 9;    // wave id * 512

    unsigned long long v[8];
#pragma unroll
    for (int r = 0; r < 8; r++) {
        int i = base | (r << 6) | lane;
        v[r] = (i < n) ? src[i] : 0ull;
    }

    StageH<2>::run(v, base, lane);             // K = 2..512, barrier-free

    // K = 1024
    lds_exchange<1024, 512>(v, lds, base, lane);
    PhaseH<1024, 256>::run(v, base, lane);

    // K = 2048
    lds_exchange<2048, 1024>(v, lds, base, lane);
    lds_exchange<2048, 512>(v, lds, base, lane);
    PhaseH<2048, 256>::run(v, base, lane);

#pragma unroll
    for (int r = 0; r < 8; r++) src[base | (r << 6) | lane] = v[r];
}

// ---------------- build det: concat(hi,bd), validity, stable partition, write rows ----------------
__global__ __launch_bounds__(1024) void build_kernel(
    const float* __restrict__ t0, const float* __restrict__ t1, const float* __restrict__ t2,
    const float* __restrict__ r0, const float* __restrict__ r1, const float* __restrict__ r2,
    const int* __restrict__ cnt, const unsigned long long* __restrict__ cand,
    float* __restrict__ det)
{
    int l = blockIdx.x >> 4;
    int b = blockIdx.x & 15;
    int bl = l * 16 + b;
    int HW = (l == 0) ? 16384 : (l == 1) ? 4096 : 1024;
    int W  = (l == 0) ? 128 : (l == 1) ? 64 : 32;
    int K  = (l == 2) ? 1024 : 2000;
    float scale = (l == 0) ? 8.f : (l == 1) ? 16.f : 32.f;
    const float* tlp = (l == 0) ? t0 : (l == 1) ? t1 : t2;
    const float* brp = (l == 0) ? r0 : (l == 1) ? r1 : r2;

    int n_hi = min(cnt[bl * 2], CAP2);
    const unsigned long long* hi = cand + (size_t)(bl * 2) * CAP2;
    const unsigned long long* bd = cand + (size_t)(bl * 2 + 1) * CAP2;

    __shared__ int wsum[16];
    int tid = threadIdx.x;
    int lane = tid & 63, wid = tid >> 6;

    // each thread handles k = 2*tid, 2*tid+1 (consecutive -> correct scan order)
    float s_[2], bx_[2][4];
    int f_[2];
#pragma unroll
    for (int q = 0; q < 2; q++) {
        int k = 2 * tid + q;
        f_[q] = 0;
        if (k < K) {
            unsigned long long kk = (k < n_hi) ? hi[k] : bd[k - n_hi];
            unsigned int idx = ~(unsigned int)kk;
            float score = unord_f32((unsigned int)(kk >> 32));
            int sp = (int)(idx % (unsigned)HW);
            float xs = (float)(sp % W), ys = (float)(sp / W);
            float tv0 = tlp[((size_t)b * 2 + 0) * HW + sp];
            float tv1 = tlp[((size_t)b * 2 + 1) * HW + sp];
            float bv0 = brp[((size_t)b * 2 + 0) * HW + sp];
            float bv1 = brp[((size_t)b * 2 + 1) * HW + sp];
            float tlx = __fsub_rn(xs, __fadd_rn(__fmul_rn(1.5f, tv0), 2.25f));
            float tly = __fsub_rn(ys, __fadd_rn(__fmul_rn(1.5f, tv1), 2.25f));
            float brx = __fadd_rn(xs, __fadd_rn(__fmul_rn(1.5f, bv0), 2.25f));
            float bry = __fadd_rn(ys, __fadd_rn(__fmul_rn(1.5f, bv1), 2.25f));
            bool invalid = (brx < tlx) || (bry < tly);
            f_[q] = invalid ? 0 : 1;
            s_[q] = invalid ? -1.0f : score;
            bx_[q][0] = __fmul_rn(tlx, scale);
            bx_[q][1] = __fmul_rn(tly, scale);
            bx_[q][2] = __fmul_rn(brx, scale);
            bx_[q][3] = __fmul_rn(bry, scale);
        }
    }
    int mysum = f_[0] + f_[1];

    // wave-level inclusive scan of mysum
    int x = mysum;
#pragma unroll
    for (int off = 1; off < 64; off <<= 1) {
        int y = __shfl_up(x, off, 64);
        if (lane >= off) x += y;
    }
    if (lane == 63) wsum[wid] = x;
    __syncthreads();
    if (wid == 0 && lane < 16) {
        int s = wsum[lane];
#pragma unroll
        for (int off = 1; off < 16; off <<= 1) {
            int y = __shfl_up(s, off, 64);
            if (lane >= off) s += y;
        }
        wsum[lane] = s;   // inclusive per-wave prefix
    }
    __syncthreads();
    int wave_off = (wid > 0) ? wsum[wid - 1] : 0;
    int V = wsum[15];
    int base_excl = (x + wave_off) - mysum;   // # valid strictly before element 2*tid

    float* dbase = det + ((size_t)b * 3000 + (size_t)l * 1000) * 7;
#pragma unroll
    for (int q = 0; q < 2; q++) {
        int k = 2 * tid + q;
        if (k < K) {
            int pos = base_excl + (q == 1 ? f_[0] : 0);   // # valid before k
            int rank = f_[q] ? pos : V + (k - pos);
            if (rank < 1000 && rank != 6) {
                float* drow = dbase + (size_t)rank * 7;
                drow[0] = s_[q];
                drow[1] = bx_[q][0];
                drow[2] = bx_[q][1];
                drow[3] = bx_[q][2];
                drow[4] = bx_[q][3];
                drow[5] = 0.f;
                drow[6] = 0.f;
            }
        }
    }
    if (tid == 0) {
        float lv = (float)l;
        float* drow = dbase + 6 * 7;
#pragma unroll
        for (int j = 0; j < 7; j++) drow[j] = lv;
    }
}

// ---------------- final: merge-rank of 3 sorted lists (+3 clobbered singletons) ----------------
__device__ __forceinline__ bool key_gt(float sa, int ga, float sb, int gb) {
    return (sa > sb) || (sa == sb && ga < gb);
}

__global__ __launch_bounds__(1024) void final_kernel(const float* __restrict__ det,
                                                     float* __restrict__ out)
{
    int b = blockIdx.x;
    __shared__ float sc[3000];
    int tid = threadIdx.x;
    const float* dbase = det + (size_t)b * 3000 * 7;
    for (int i = tid; i < 3000; i += 1024) sc[i] = dbase[(size_t)i * 7];
    __syncthreads();

    for (int e = tid; e < 3000; e += 1024) {
        float se = sc[e];
        int ge = e;
        int rank = 0;
#pragma unroll
        for (int lp = 0; lp < 3; lp++) {
            int lo = 0, hiB = 999;
            while (lo < hiB) {
                int mid = (lo + hiB) >> 1;
                int p = mid + (mid >= 6 ? 1 : 0);
                int g = lp * 1000 + p;
                if (key_gt(sc[g], g, se, ge)) lo = mid + 1; else hiB = mid;
            }
            rank += lo;
        }
#pragma unroll
        for (int ls = 0; ls < 3; ls++) {
            int g = ls * 1000 + 6;
            if (g != e && key_gt((float)ls, g, se, ge)) rank++;
        }
        if (rank < 1000) {
            const float* src = dbase + (size_t)e * 7;
            float* dst = out + ((size_t)b * 1000 + rank) * 7;
#pragma unroll
            for (int j = 0; j < 7; j++) dst[j] = src[j];
        }
    }
}

extern "C" void kernel_launch(void* const* d_in, const int* in_sizes, int n_in,
                              void* d_out, int out_size, void* d_ws, size_t ws_size,
                              hipStream_t stream)
{
    (void)in_sizes; (void)n_in; (void)out_size; (void)ws_size;
    const float* h0 = (const float*)d_in[0];
    const float* t0 = (const float*)d_in[1];
    const float* r0 = (const float*)d_in[2];
    const float* h1 = (const float*)d_in[3];
    const float* t1 = (const float*)d_in[4];
    const float* r1 = (const float*)d_in[5];
    const float* h2 = (const float*)d_in[6];
    const float* t2 = (const float*)d_in[7];
    const float* r2 = (const float*)d_in[8];
    float* out = (float*)d_out;

    // Workspace layout (bytes):
    //   ph  : 848*1024*4 = 3473408   @ 0
    //   cnt : 96*4       = 384       @ 3473408  (zeroed by thresh_kernel)
    //   tb  : 48*4       = 192       @ 3473792
    //   cand: 96*2048*8  = 1572864   @ 3473984  (8B aligned)
    //   det : 16*3000*7*4= 1344000   @ 5046848
    char* ws = (char*)d_ws;
    int* ph   = (int*)ws;
    int* cnt  = (int*)(ws + 3473408);
    int* tb   = (int*)(ws + 3473792);
    unsigned long long* cand = (unsigned long long*)(ws + 3473984);
    float* det = (float*)(ws + 5046848);

    hist_kernel<<<dim3(40, 16, 3), 256, 0, stream>>>(h0, h1, h2, ph);
    thresh_kernel<<<48, 256, 0, stream>>>(ph, tb, cnt);
    collect_kernel<<<dim3(80, 16, 3), 256, 0, stream>>>(h0, h1, h2, tb, cnt, cand);
    sort_kernel<<<96, 256, 0, stream>>>(cnt, cand);
    build_kernel<<<48, 1024, 0, stream>>>(t0, t1, t2, r0, r1, r2, cnt, cand, det);
    final_kernel<<<16, 1024, 0, stream>>>(det, out);
}

// Round 7
// 255.736 us; speedup vs baseline: 1.7275x; 1.0043x over previous
//
#include <hip/hip_runtime.h>

// B=16, C=80, layer sizes 128/64/32.
// d_in order: heat0, tl0, br0, heat1, tl1, br1, heat2, tl2, br2.

#define NB 1024      // histogram buckets over score in [0,1)
#define CAP2 2048    // capacity per candidate sub-list (hi / boundary)
#define CHUNK 32768  // elements per fused block

__device__ __forceinline__ unsigned int ord_f32(float f) {
    unsigned int b = __float_as_uint(f);
    return (b & 0x80000000u) ? ~b : (b | 0x80000000u);
}
__device__ __forceinline__ float unord_f32(unsigned int o) {
    unsigned int b = (o & 0x80000000u) ? (o & 0x7fffffffu) : ~o;
    return __uint_as_float(b);
}
__device__ __forceinline__ int bucket_of(float f) {
    int bi = (int)(f * (float)NB);
    bi = bi < 0 ? 0 : (bi > NB - 1 ? NB - 1 : bi);
    return bi;
}

__device__ __forceinline__ int layer_N(int l)  { return (l == 0) ? 1310720 : (l == 1) ? 327680 : 81920; }
__device__ __forceinline__ int nchunks(int l)  { return (l == 0) ? 40 : (l == 1) ? 10 : 3; }
__device__ __forceinline__ int hist_base(int l){ return (l == 0) ? 0 : (l == 1) ? 640 : 800; }
// total partials: 40*16 + 10*16 + 3*16 = 848
__device__ __forceinline__ int TL_of(int l)    { return (l == 0) ? NB - 4 : (l == 1) ? NB - 16 : NB - 32; }
__device__ __forceinline__ int bl_cap(int l)   { return (l == 0) ? 512 : (l == 1) ? 1024 : 2048; }
__device__ __forceinline__ int loose_base(int l){ return (l == 0) ? 0 : (l == 1) ? 327680 : 491520; } // entries
// loose total: 640*512 + 160*1024 + 48*2048 = 589824 entries

// ---------------- fused: one heat pass -> partial hist + loose candidates ----------------
__global__ __launch_bounds__(256) void fused_kernel(
    const float* __restrict__ h0, const float* __restrict__ h1, const float* __restrict__ h2,
    int* __restrict__ ph, int* __restrict__ pbc, unsigned long long* __restrict__ loose)
{
    int l = blockIdx.z, b = blockIdx.y, chunk = blockIdx.x;
    int nc = nchunks(l);
    if (chunk >= nc) return;
    int N = layer_N(l);
    int elems = min(CHUNK, N - chunk * CHUNK);
    const float* heat = (l == 0) ? h0 : (l == 1) ? h1 : h2;
    int TL = TL_of(l);

    __shared__ int lh[NB];
    __shared__ int lc;
    __shared__ unsigned long long lbuf[2048];
    for (int i = threadIdx.x; i < NB; i += 256) lh[i] = 0;
    if (threadIdx.x == 0) lc = 0;
    __syncthreads();

    const float4* p = (const float4*)(heat + (size_t)b * N + (size_t)chunk * CHUNK);
    int base = chunk * CHUNK;
    int n4 = elems >> 2;
    for (int i = threadIdx.x; i < n4; i += 256) {
        float4 v = p[i];
        float vs[4] = {v.x, v.y, v.z, v.w};
#pragma unroll
        for (int cc = 0; cc < 4; cc++) {
            int bk = bucket_of(vs[cc]);
            atomicAdd(&lh[bk], 1);
            if (bk >= TL) {
                int pos = atomicAdd(&lc, 1);
                if (pos < 2048) {
                    unsigned int idx = (unsigned int)(base + 4 * i + cc);
                    lbuf[pos] = ((unsigned long long)ord_f32(vs[cc]) << 32) | (unsigned int)(~idx);
                }
            }
        }
    }
    __syncthreads();
    int pidx = hist_base(l) + b * nc + chunk;
    int* dst = ph + (size_t)pidx * NB;
    for (int i = threadIdx.x; i < NB; i += 256) dst[i] = lh[i];
    if (threadIdx.x == 0) pbc[pidx] = lc;   // raw count (overflow detectable)
    int cap = bl_cap(l);
    int n = min(lc, min(cap, 2048));
    unsigned long long* seg = loose + loose_base(l) + (size_t)(b * nc + chunk) * cap;
    for (int i = threadIdx.x; i < n; i += 256) seg[i] = lbuf[i];
}

// ---------------- merged threshold + partition (exact; repair fallback) ----------------
__global__ __launch_bounds__(256) void partition_kernel(
    const float* __restrict__ h0, const float* __restrict__ h1, const float* __restrict__ h2,
    const int* __restrict__ ph, const int* __restrict__ pbc,
    const unsigned long long* __restrict__ loose,
    int* __restrict__ cnt, unsigned long long* __restrict__ cand)
{
    int b = blockIdx.x & 15;
    int l = blockIdx.x >> 4;
    int bl = l * 16 + b;
    int K = (l == 2) ? 1024 : 2000;
    int nc = nchunks(l);
    int cap = bl_cap(l);
    const int* hbase = ph + (size_t)(hist_base(l) + b * nc) * NB;

    __shared__ int hh[NB];
    __shared__ int seg[256];
    __shared__ int st;       // exact threshold bucket
    __shared__ int repf;     // repair flag
    __shared__ int lc[2];
    __shared__ unsigned long long lbuf[2][2048];
    int tid = threadIdx.x;

    // 1. reduce partial hists
    int s4 = 0;
    for (int j = 0; j < 4; j++) {
        int bkt = tid * 4 + j;
        int s = 0;
        for (int c = 0; c < nc; c++) s += hbase[(size_t)c * NB + bkt];
        hh[bkt] = s;
        s4 += s;
    }
    seg[tid] = s4;
    if (tid == 0) { repf = 0; lc[0] = 0; lc[1] = 0; }
    __syncthreads();
    // 2. exact threshold scan (thread 0)
    if (tid == 0) {
        int acc = 0, si;
        for (si = 255; si >= 0; si--) {
            if (acc + seg[si] >= K) break;
            acc += seg[si];
        }
        if (si < 0) si = 0;  // defensive
        int bidx = si * 4 + 3;
        for (; bidx > si * 4; bidx--) {
            acc += hh[bidx];
            if (acc >= K) break;
        }
        st = bidx;
        if (bidx < TL_of(l)) repf = 1;   // loose lists don't cover exact t
    }
    __syncthreads();
    int t = st;
    // 3. overflow check on loose segments
    for (int c = tid; c < nc; c += 256)
        if (pbc[hist_base(l) + b * nc + c] > min(cap, 2048)) repf = 1;
    __syncthreads();

    if (!repf) {
        // 4a. partition loose list by exact t
        const unsigned long long* lb = loose + loose_base(l) + (size_t)b * nc * cap;
        for (int c = 0; c < nc; c++) {
            int n_c = min(pbc[hist_base(l) + b * nc + c], min(cap, 2048));
            const unsigned long long* sg = lb + (size_t)c * cap;
            for (int i = tid; i < n_c; i += 256) {
                unsigned long long key = sg[i];
                int bk = bucket_of(unord_f32((unsigned int)(key >> 32)));
                if (bk >= t) {
                    int which = (bk > t) ? 0 : 1;
                    int pos = atomicAdd(&lc[which], 1);
                    if (pos < 2048) lbuf[which][pos] = key;
                }
            }
        }
    } else {
        // 4b. repair: exact rescan of this (b,l)'s heat (never triggers for sane inputs)
        int N = layer_N(l);
        const float* heat = (l == 0) ? h0 : (l == 1) ? h1 : h2;
        const float4* p = (const float4*)(heat + (size_t)b * N);
        for (int i = tid; i < (N >> 2); i += 256) {
            float4 v = p[i];
            float vs[4] = {v.x, v.y, v.z, v.w};
#pragma unroll
            for (int cc = 0; cc < 4; cc++) {
                int bk = bucket_of(vs[cc]);
                if (bk >= t) {
                    int which = (bk > t) ? 0 : 1;
                    int pos = atomicAdd(&lc[which], 1);
                    if (pos < 2048) {
                        unsigned int idx = (unsigned int)(4 * i + cc);
                        lbuf[which][pos] = ((unsigned long long)ord_f32(vs[cc]) << 32) | (unsigned int)(~idx);
                    }
                }
            }
        }
    }
    __syncthreads();
    // 5. flush hi/bd lists (single block per bl -> direct write, no atomics)
#pragma unroll
    for (int w = 0; w < 2; w++) {
        int n = min(lc[w], CAP2);
        if (tid == 0) cnt[bl * 2 + w] = n;
        unsigned long long* cd = cand + ((size_t)bl * 2 + w) * CAP2;
        for (int i = tid; i < n; i += 256) cd[i] = lbuf[w][i];
    }
}

// ---------------- 4-wave hybrid bitonic sort of 2048 u64 keys, descending ----------------
// Each wave owns 512 elements: i = (wid<<9) | (r<<6) | lane, r in [0,8).
// Stages K=2..512: barrier-free (register pairs for strides 64..256, shfl_xor <64).
// Stages K=1024/2048: 3 LDS exchanges + barrier-free local strides.
// (R4: runtime indices -> scratch, 204us. R5: 1 wave/list -> DS-issue bound, 59us.)

__device__ __forceinline__ unsigned long long shfl_xor_u64(unsigned long long a, int j) {
    unsigned int lo = (unsigned int)a, hi = (unsigned int)(a >> 32);
    lo = (unsigned int)__shfl_xor((int)lo, j, 64);
    hi = (unsigned int)__shfl_xor((int)hi, j, 64);
    return ((unsigned long long)hi << 32) | lo;
}

template<int K, int J>
struct PhaseH {
    static __device__ __forceinline__ void run(unsigned long long (&v)[8], int base, int lane) {
        constexpr int JR = J >> 6;   // 64 <= J <= 256 here -> JR in {1,2,4}
#pragma unroll
        for (int r = 0; r < 8; r++) {
            if ((r & JR) == 0) {
                int i = base | (r << 6) | lane;
                unsigned long long a = v[r], bb = v[r | JR];
                bool sw = ((i & K) == 0) ? (a < bb) : (a > bb);
                if (sw) { v[r] = bb; v[r | JR] = a; }
            }
        }
        PhaseH<K, (J >> 1)>::run(v, base, lane);
    }
};

template<int K>
struct PhaseH<K, 32> {
    static __device__ __forceinline__ void run(unsigned long long (&v)[8], int base, int lane) {
#pragma unroll
        for (int js = 32; js >= 1; js >>= 1) {
            if (K > js) {
#pragma unroll
                for (int r = 0; r < 8; r++) {
                    unsigned long long a = v[r];
                    unsigned long long w = shfl_xor_u64(a, js);
                    int i = base | (r << 6) | lane;
                    bool upper = (lane & js) != 0;
                    bool keep_max = (((i & K) == 0) != upper);
                    bool agw = a > w;
                    v[r] = (keep_max == agw) ? a : w;
                }
            }
        }
    }
};

template<int K>
struct StageH {
    static __device__ __forceinline__ void run(unsigned long long (&v)[8], int base, int lane) {
        PhaseH<K, (K > 64 ? (K >> 1) : 32)>::run(v, base, lane);
        StageH<(K << 1)>::run(v, base, lane);
    }
};
template<>
struct StageH<1024> {
    static __device__ __forceinline__ void run(unsigned long long (&)[8], int, int) {}
};

template<int K, int J>
__device__ __forceinline__ void lds_exchange(unsigned long long (&v)[8],
                                             unsigned long long* lds, int base, int lane) {
    __syncthreads();
#pragma unroll
    for (int r = 0; r < 8; r++) lds[base | (r << 6) | lane] = v[r];
    __syncthreads();
#pragma unroll
    for (int r = 0; r < 8; r++) {
        int i = base | (r << 6) | lane;
        unsigned long long w = lds[i ^ J];
        bool upper = (i & J) != 0;
        bool keep_max = (((i & K) == 0) != upper);
        bool agw = v[r] > w;
        v[r] = (keep_max == agw) ? v[r] : w;
    }
}

__global__ __launch_bounds__(256) void sort_kernel(const int* __restrict__ cnt,
                                                   unsigned long long* __restrict__ cand)
{
    int idx = blockIdx.x;          // bl*2 + which
    int n = min(cnt[idx], CAP2);
    unsigned long long* src = cand + (size_t)idx * CAP2;
    __shared__ unsigned long long lds[CAP2];
    int tid = threadIdx.x;
    int lane = tid & 63;
    int base = (tid >> 6) << 9;    // wave id * 512

    unsigned long long v[8];
#pragma unroll
    for (int r = 0; r < 8; r++) {
        int i = base | (r << 6) | lane;
        v[r] = (i < n) ? src[i] : 0ull;
    }

    StageH<2>::run(v, base, lane);             // K = 2..512, barrier-free

    lds_exchange<1024, 512>(v, lds, base, lane);
    PhaseH<1024, 256>::run(v, base, lane);

    lds_exchange<2048, 1024>(v, lds, base, lane);
    lds_exchange<2048, 512>(v, lds, base, lane);
    PhaseH<2048, 256>::run(v, base, lane);

#pragma unroll
    for (int r = 0; r < 8; r++) src[base | (r << 6) | lane] = v[r];
}

// ---------------- build det: concat(hi,bd), validity, stable partition, write rows ----------------
__global__ __launch_bounds__(1024) void build_kernel(
    const float* __restrict__ t0, const float* __restrict__ t1, const float* __restrict__ t2,
    const float* __restrict__ r0, const float* __restrict__ r1, const float* __restrict__ r2,
    const int* __restrict__ cnt, const unsigned long long* __restrict__ cand,
    float* __restrict__ det)
{
    int l = blockIdx.x >> 4;
    int b = blockIdx.x & 15;
    int bl = l * 16 + b;
    int HW = (l == 0) ? 16384 : (l == 1) ? 4096 : 1024;
    int W  = (l == 0) ? 128 : (l == 1) ? 64 : 32;
    int K  = (l == 2) ? 1024 : 2000;
    float scale = (l == 0) ? 8.f : (l == 1) ? 16.f : 32.f;
    const float* tlp = (l == 0) ? t0 : (l == 1) ? t1 : t2;
    const float* brp = (l == 0) ? r0 : (l == 1) ? r1 : r2;

    int n_hi = min(cnt[bl * 2], CAP2);
    const unsigned long long* hi = cand + (size_t)(bl * 2) * CAP2;
    const unsigned long long* bd = cand + (size_t)(bl * 2 + 1) * CAP2;

    __shared__ int wsum[16];
    int tid = threadIdx.x;
    int lane = tid & 63, wid = tid >> 6;

    float s_[2], bx_[2][4];
    int f_[2];
#pragma unroll
    for (int q = 0; q < 2; q++) {
        int k = 2 * tid + q;
        f_[q] = 0;
        if (k < K) {
            unsigned long long kk = (k < n_hi) ? hi[k] : bd[k - n_hi];
            unsigned int idx = ~(unsigned int)kk;
            float score = unord_f32((unsigned int)(kk >> 32));
            int sp = (int)(idx % (unsigned)HW);
            float xs = (float)(sp % W), ys = (float)(sp / W);
            float tv0 = tlp[((size_t)b * 2 + 0) * HW + sp];
            float tv1 = tlp[((size_t)b * 2 + 1) * HW + sp];
            float bv0 = brp[((size_t)b * 2 + 0) * HW + sp];
            float bv1 = brp[((size_t)b * 2 + 1) * HW + sp];
            float tlx = __fsub_rn(xs, __fadd_rn(__fmul_rn(1.5f, tv0), 2.25f));
            float tly = __fsub_rn(ys, __fadd_rn(__fmul_rn(1.5f, tv1), 2.25f));
            float brx = __fadd_rn(xs, __fadd_rn(__fmul_rn(1.5f, bv0), 2.25f));
            float bry = __fadd_rn(ys, __fadd_rn(__fmul_rn(1.5f, bv1), 2.25f));
            bool invalid = (brx < tlx) || (bry < tly);
            f_[q] = invalid ? 0 : 1;
            s_[q] = invalid ? -1.0f : score;
            bx_[q][0] = __fmul_rn(tlx, scale);
            bx_[q][1] = __fmul_rn(tly, scale);
            bx_[q][2] = __fmul_rn(brx, scale);
            bx_[q][3] = __fmul_rn(bry, scale);
        }
    }
    int mysum = f_[0] + f_[1];

    int x = mysum;
#pragma unroll
    for (int off = 1; off < 64; off <<= 1) {
        int y = __shfl_up(x, off, 64);
        if (lane >= off) x += y;
    }
    if (lane == 63) wsum[wid] = x;
    __syncthreads();
    if (wid == 0 && lane < 16) {
        int s = wsum[lane];
#pragma unroll
        for (int off = 1; off < 16; off <<= 1) {
            int y = __shfl_up(s, off, 64);
            if (lane >= off) s += y;
        }
        wsum[lane] = s;
    }
    __syncthreads();
    int wave_off = (wid > 0) ? wsum[wid - 1] : 0;
    int V = wsum[15];
    int base_excl = (x + wave_off) - mysum;

    float* dbase = det + ((size_t)b * 3000 + (size_t)l * 1000) * 7;
#pragma unroll
    for (int q = 0; q < 2; q++) {
        int k = 2 * tid + q;
        if (k < K) {
            int pos = base_excl + (q == 1 ? f_[0] : 0);
            int rank = f_[q] ? pos : V + (k - pos);
            if (rank < 1000 && rank != 6) {
                float* drow = dbase + (size_t)rank * 7;
                drow[0] = s_[q];
                drow[1] = bx_[q][0];
                drow[2] = bx_[q][1];
                drow[3] = bx_[q][2];
                drow[4] = bx_[q][3];
                drow[5] = 0.f;
                drow[6] = 0.f;
            }
        }
    }
    if (tid == 0) {
        float lv = (float)l;
        float* drow = dbase + 6 * 7;
#pragma unroll
        for (int j = 0; j < 7; j++) drow[j] = lv;
    }
}

// ---------------- final: merge-rank of 3 sorted lists (+3 clobbered singletons) ----------------
__device__ __forceinline__ bool key_gt(float sa, int ga, float sb, int gb) {
    return (sa > sb) || (sa == sb && ga < gb);
}

__global__ __launch_bounds__(1024) void final_kernel(const float* __restrict__ det,
                                                     float* __restrict__ out)
{
    int b = blockIdx.x;
    __shared__ float sc[3000];
    int tid = threadIdx.x;
    const float* dbase = det + (size_t)b * 3000 * 7;
    for (int i = tid; i < 3000; i += 1024) sc[i] = dbase[(size_t)i * 7];
    __syncthreads();

    for (int e = tid; e < 3000; e += 1024) {
        float se = sc[e];
        int ge = e;
        int rank = 0;
#pragma unroll
        for (int lp = 0; lp < 3; lp++) {
            int lo = 0, hiB = 999;
            while (lo < hiB) {
                int mid = (lo + hiB) >> 1;
                int p = mid + (mid >= 6 ? 1 : 0);
                int g = lp * 1000 + p;
                if (key_gt(sc[g], g, se, ge)) lo = mid + 1; else hiB = mid;
            }
            rank += lo;
        }
#pragma unroll
        for (int ls = 0; ls < 3; ls++) {
            int g = ls * 1000 + 6;
            if (g != e && key_gt((float)ls, g, se, ge)) rank++;
        }
        if (rank < 1000) {
            const float* src = dbase + (size_t)e * 7;
            float* dst = out + ((size_t)b * 1000 + rank) * 7;
#pragma unroll
            for (int j = 0; j < 7; j++) dst[j] = src[j];
        }
    }
}

extern "C" void kernel_launch(void* const* d_in, const int* in_sizes, int n_in,
                              void* d_out, int out_size, void* d_ws, size_t ws_size,
                              hipStream_t stream)
{
    (void)in_sizes; (void)n_in; (void)out_size; (void)ws_size;
    const float* h0 = (const float*)d_in[0];
    const float* t0 = (const float*)d_in[1];
    const float* r0 = (const float*)d_in[2];
    const float* h1 = (const float*)d_in[3];
    const float* t1 = (const float*)d_in[4];
    const float* r1 = (const float*)d_in[5];
    const float* h2 = (const float*)d_in[6];
    const float* t2 = (const float*)d_in[7];
    const float* r2 = (const float*)d_in[8];
    float* out = (float*)d_out;

    // Workspace layout (bytes):
    //   ph   : 848*1024*4  = 3473408   @ 0
    //   pbc  : 848*4       = 3392      @ 3473408
    //   loose: 589824*8    = 4718592   @ 3476800  (8B aligned)
    //   cnt  : 96*4        = 384       @ 8195392
    //   cand : 96*2048*8   = 1572864   @ 8195776  (8B aligned)
    //   det  : 16*3000*7*4 = 1344000   @ 9768640
    char* ws = (char*)d_ws;
    int* ph   = (int*)ws;
    int* pbc  = (int*)(ws + 3473408);
    unsigned long long* loose = (unsigned long long*)(ws + 3476800);
    int* cnt  = (int*)(ws + 8195392);
    unsigned long long* cand  = (unsigned long long*)(ws + 8195776);
    float* det = (float*)(ws + 9768640);

    fused_kernel<<<dim3(40, 16, 3), 256, 0, stream>>>(h0, h1, h2, ph, pbc, loose);
    partition_kernel<<<48, 256, 0, stream>>>(h0, h1, h2, ph, pbc, loose, cnt, cand);
    sort_kernel<<<96, 256, 0, stream>>>(cnt, cand);
    build_kernel<<<48, 1024, 0, stream>>>(t0, t1, t2, r0, r1, r2, cnt, cand, det);
    final_kernel<<<16, 1024, 0, stream>>>(det, out);
}

// Round 8
// 249.563 us; speedup vs baseline: 1.7703x; 1.0247x over previous
//
#include <hip/hip_runtime.h>

// B=16, C=80, layer sizes 128/64/32.
// d_in order: heat0, tl0, br0, heat1, tl1, br1, heat2, tl2, br2.
//
// Static-threshold design (R8): collect all heat elements >= T(l) (binomial
// margins >11 sigma for uniform inputs), sort the whole 4096-padded candidate
// list exactly by (score desc, idx asc), take first K. No histogram pass.
// sort_kernel carries an exact LDS-hist repair path for pathological inputs.

#define NB 1024      // repair-path histogram buckets
#define CHUNK 32768  // elements per collect block

__device__ __forceinline__ unsigned int ord_f32(float f) {
    unsigned int b = __float_as_uint(f);
    return (b & 0x80000000u) ? ~b : (b | 0x80000000u);
}
__device__ __forceinline__ float unord_f32(unsigned int o) {
    unsigned int b = (o & 0x80000000u) ? (o & 0x7fffffffu) : ~o;
    return __uint_as_float(b);
}
__device__ __forceinline__ int bucket_of(float f) {
    int bi = (int)(f * (float)NB);
    bi = bi < 0 ? 0 : (bi > NB - 1 ? NB - 1 : bi);
    return bi;
}

__device__ __forceinline__ int layer_N(int l)   { return (l == 0) ? 1310720 : (l == 1) ? 327680 : 81920; }
__device__ __forceinline__ int nchunks(int l)   { return (l == 0) ? 40 : (l == 1) ? 10 : 3; }
__device__ __forceinline__ int chunk_base(int l){ return (l == 0) ? 0 : (l == 1) ? 640 : 800; }
// chunk slots: 40*16 + 10*16 + 3*16 = 848
__device__ __forceinline__ float TL_of(int l)   { return (l == 0) ? 0.998046875f : (l == 1) ? 0.9921875f : 0.98125f; }
// expected counts per (b,l): 2560 / 2560 / 1536; bounds [K, 4096] at >11 sigma
__device__ __forceinline__ int seg_cap(int l)   { return (l == 0) ? 256 : (l == 1) ? 768 : 1024; }
// per-chunk expected: 64 / 256 / 614 -> caps at 24/32/16 sigma
__device__ __forceinline__ int loose_base(int l){ return (l == 0) ? 0 : (l == 1) ? 163840 : 286720; } // entries
// loose total: 40*16*256 + 10*16*768 + 3*16*1024 = 335872 entries

// ---------------- collect: one heat pass, static threshold, segment write ----------------
__global__ __launch_bounds__(256) void collect_kernel(
    const float* __restrict__ h0, const float* __restrict__ h1, const float* __restrict__ h2,
    int* __restrict__ pbc, unsigned long long* __restrict__ loose)
{
    int l = blockIdx.z, b = blockIdx.y, chunk = blockIdx.x;
    int nc = nchunks(l);
    if (chunk >= nc) return;
    int N = layer_N(l);
    int elems = min(CHUNK, N - chunk * CHUNK);
    const float* heat = (l == 0) ? h0 : (l == 1) ? h1 : h2;
    float TL = TL_of(l);

    __shared__ int lc;
    __shared__ unsigned long long lbuf[1024];
    if (threadIdx.x == 0) lc = 0;
    __syncthreads();

    const float4* p = (const float4*)(heat + (size_t)b * N + (size_t)chunk * CHUNK);
    int base = chunk * CHUNK;
    int n4 = elems >> 2;
    for (int i = threadIdx.x; i < n4; i += 256) {
        float4 v = p[i];
        float vs[4] = {v.x, v.y, v.z, v.w};
#pragma unroll
        for (int cc = 0; cc < 4; cc++) {
            if (vs[cc] >= TL) {
                int pos = atomicAdd(&lc, 1);
                if (pos < 1024) {
                    unsigned int idx = (unsigned int)(base + 4 * i + cc);
                    lbuf[pos] = ((unsigned long long)ord_f32(vs[cc]) << 32) | (unsigned int)(~idx);
                }
            }
        }
    }
    __syncthreads();
    int pidx = chunk_base(l) + b * nc + chunk;
    if (threadIdx.x == 0) pbc[pidx] = lc;   // raw count (overflow detectable)
    int cap = seg_cap(l);
    int n = min(lc, cap);
    unsigned long long* seg = loose + loose_base(l) + (size_t)(b * nc + chunk) * cap;
    for (int i = threadIdx.x; i < n; i += 256) seg[i] = lbuf[i];
}

// ---------------- 4-wave hybrid bitonic sort of 4096 u64 keys, descending ----------------
// Each wave owns 1024 contiguous elements: i = (wid<<10) | (r<<6) | lane, r in [0,16).
// Stages K=2..1024 fully intra-wave (reg strides 64..512 -> JR 1..8, shfl <64).
// K=2048: 1 LDS exchange; K=4096: 2 LDS exchanges. All register indices static.

__device__ __forceinline__ unsigned long long shfl_xor_u64(unsigned long long a, int j) {
    unsigned int lo = (unsigned int)a, hi = (unsigned int)(a >> 32);
    lo = (unsigned int)__shfl_xor((int)lo, j, 64);
    hi = (unsigned int)__shfl_xor((int)hi, j, 64);
    return ((unsigned long long)hi << 32) | lo;
}

template<int K, int J>
struct P16 {
    static __device__ __forceinline__ void run(unsigned long long (&v)[16], int base, int lane) {
        constexpr int JR = J >> 6;   // J in 64..512 -> JR in {1,2,4,8}
#pragma unroll
        for (int r = 0; r < 16; r++) {
            if ((r & JR) == 0) {
                int i = base | (r << 6) | lane;
                unsigned long long a = v[r], bb = v[r | JR];
                bool sw = ((i & K) == 0) ? (a < bb) : (a > bb);
                if (sw) { v[r] = bb; v[r | JR] = a; }
            }
        }
        P16<K, (J >> 1)>::run(v, base, lane);
    }
};

template<int K>
struct P16<K, 32> {
    static __device__ __forceinline__ void run(unsigned long long (&v)[16], int base, int lane) {
#pragma unroll
        for (int js = 32; js >= 1; js >>= 1) {
            if (K > js) {
#pragma unroll
                for (int r = 0; r < 16; r++) {
                    unsigned long long a = v[r];
                    unsigned long long w = shfl_xor_u64(a, js);
                    int i = base | (r << 6) | lane;
                    bool upper = (lane & js) != 0;
                    bool keep_max = (((i & K) == 0) != upper);
                    bool agw = a > w;
                    v[r] = (keep_max == agw) ? a : w;
                }
            }
        }
    }
};

template<int K>
struct S16 {
    static __device__ __forceinline__ void run(unsigned long long (&v)[16], int base, int lane) {
        P16<K, (K > 64 ? (K >> 1) : 32)>::run(v, base, lane);
        S16<(K << 1)>::run(v, base, lane);
    }
};
template<>
struct S16<2048> {
    static __device__ __forceinline__ void run(unsigned long long (&)[16], int, int) {}
};

template<int K, int J>
__device__ __forceinline__ void lds_exchange16(unsigned long long (&v)[16],
                                               unsigned long long* lds, int base, int lane) {
    __syncthreads();
#pragma unroll
    for (int r = 0; r < 16; r++) lds[base | (r << 6) | lane] = v[r];
    __syncthreads();
#pragma unroll
    for (int r = 0; r < 16; r++) {
        int i = base | (r << 6) | lane;
        unsigned long long w = lds[i ^ J];
        bool upper = (i & J) != 0;
        bool keep_max = (((i & K) == 0) != upper);
        bool agw = v[r] > w;
        v[r] = (keep_max == agw) ? v[r] : w;
    }
}

__global__ __launch_bounds__(256) void sort_kernel(
    const float* __restrict__ h0, const float* __restrict__ h1, const float* __restrict__ h2,
    const int* __restrict__ pbc, const unsigned long long* __restrict__ loose,
    unsigned long long* __restrict__ cand)
{
    int bl = blockIdx.x;
    int l = bl >> 4, b = bl & 15;
    int K = (l == 2) ? 1024 : 2000;
    int nc = nchunks(l);
    int cap = seg_cap(l);
    int tid = threadIdx.x;
    int lane = tid & 63;
    int base = (tid >> 6) << 10;   // wave id * 1024

    __shared__ unsigned long long lds[4096];
    __shared__ int offs[41];
    __shared__ int s_bad, s_tot;

    // gather loose segments into LDS (order irrelevant: sort is total)
    if (tid == 0) {
        int o = 0, bad = 0;
        const int* pb = pbc + chunk_base(l) + b * nc;
        for (int c = 0; c < nc; c++) {
            int raw = pb[c];
            if (raw > cap) bad = 1;
            offs[c] = o;
            o += min(raw, cap);
        }
        offs[nc] = o;
        if (o < K || o > 4096) bad = 1;
        s_bad = bad;
        s_tot = o;
    }
    __syncthreads();

    if (!s_bad) {
        const unsigned long long* lb = loose + loose_base(l) + (size_t)b * nc * cap;
        for (int c = 0; c < nc; c++) {
            int o = offs[c], n_c = offs[c + 1] - o;
            const unsigned long long* sg = lb + (size_t)c * cap;
            for (int i = tid; i < n_c; i += 256) lds[o + i] = sg[i];
        }
        for (int i = s_tot + tid; i < 4096; i += 256) lds[i] = 0ull;
    } else {
        // exact repair: LDS-hist rescan of this (b,l)'s heat (never for uniform inputs)
        __shared__ int lh[NB];
        __shared__ int st, lc2;
        for (int i = tid; i < NB; i += 256) lh[i] = 0;
        if (tid == 0) lc2 = 0;
        __syncthreads();
        int N = layer_N(l);
        const float* hp = ((l == 0) ? h0 : (l == 1) ? h1 : h2) + (size_t)b * N;
        for (int i = tid; i < N; i += 256) atomicAdd(&lh[bucket_of(hp[i])], 1);
        __syncthreads();
        if (tid == 0) {
            int acc = 0, bidx;
            for (bidx = NB - 1; bidx > 0; bidx--) {
                acc += lh[bidx];
                if (acc >= K) break;
            }
            st = bidx;
        }
        __syncthreads();
        int t = st;
        for (int i = tid; i < N; i += 256) {
            float x = hp[i];
            if (bucket_of(x) >= t) {
                int pos = atomicAdd(&lc2, 1);
                if (pos < 4096)
                    lds[pos] = ((unsigned long long)ord_f32(x) << 32) | (unsigned int)(~(unsigned int)i);
            }
        }
        __syncthreads();
        for (int i = min(lc2, 4096) + tid; i < 4096; i += 256) lds[i] = 0ull;
    }
    __syncthreads();

    unsigned long long v[16];
#pragma unroll
    for (int r = 0; r < 16; r++) v[r] = lds[base | (r << 6) | lane];

    S16<2>::run(v, base, lane);                   // K = 2..1024, barrier-free

    lds_exchange16<2048, 1024>(v, lds, base, lane);
    P16<2048, 512>::run(v, base, lane);

    lds_exchange16<4096, 2048>(v, lds, base, lane);
    lds_exchange16<4096, 1024>(v, lds, base, lane);
    P16<4096, 512>::run(v, base, lane);

    unsigned long long* cd = cand + (size_t)bl * 4096;
#pragma unroll
    for (int r = 0; r < 16; r++) cd[base | (r << 6) | lane] = v[r];
}

// ---------------- build det: validity, stable partition, write rows ----------------
__global__ __launch_bounds__(1024) void build_kernel(
    const float* __restrict__ t0, const float* __restrict__ t1, const float* __restrict__ t2,
    const float* __restrict__ r0, const float* __restrict__ r1, const float* __restrict__ r2,
    const unsigned long long* __restrict__ cand, float* __restrict__ det)
{
    int l = blockIdx.x >> 4;
    int b = blockIdx.x & 15;
    int bl = l * 16 + b;
    int HW = (l == 0) ? 16384 : (l == 1) ? 4096 : 1024;
    int W  = (l == 0) ? 128 : (l == 1) ? 64 : 32;
    int K  = (l == 2) ? 1024 : 2000;
    float scale = (l == 0) ? 8.f : (l == 1) ? 16.f : 32.f;
    const float* tlp = (l == 0) ? t0 : (l == 1) ? t1 : t2;
    const float* brp = (l == 0) ? r0 : (l == 1) ? r1 : r2;

    const unsigned long long* srt = cand + (size_t)bl * 4096;

    __shared__ int wsum[16];
    int tid = threadIdx.x;
    int lane = tid & 63, wid = tid >> 6;

    // each thread handles k = 2*tid, 2*tid+1 (consecutive -> correct scan order)
    float s_[2], bx_[2][4];
    int f_[2];
#pragma unroll
    for (int q = 0; q < 2; q++) {
        int k = 2 * tid + q;
        f_[q] = 0;
        if (k < K) {
            unsigned long long kk = srt[k];
            unsigned int idx = ~(unsigned int)kk;
            float score = unord_f32((unsigned int)(kk >> 32));
            int sp = (int)(idx % (unsigned)HW);
            float xs = (float)(sp % W), ys = (float)(sp / W);
            float tv0 = tlp[((size_t)b * 2 + 0) * HW + sp];
            float tv1 = tlp[((size_t)b * 2 + 1) * HW + sp];
            float bv0 = brp[((size_t)b * 2 + 0) * HW + sp];
            float bv1 = brp[((size_t)b * 2 + 1) * HW + sp];
            float tlx = __fsub_rn(xs, __fadd_rn(__fmul_rn(1.5f, tv0), 2.25f));
            float tly = __fsub_rn(ys, __fadd_rn(__fmul_rn(1.5f, tv1), 2.25f));
            float brx = __fadd_rn(xs, __fadd_rn(__fmul_rn(1.5f, bv0), 2.25f));
            float bry = __fadd_rn(ys, __fadd_rn(__fmul_rn(1.5f, bv1), 2.25f));
            bool invalid = (brx < tlx) || (bry < tly);
            f_[q] = invalid ? 0 : 1;
            s_[q] = invalid ? -1.0f : score;
            bx_[q][0] = __fmul_rn(tlx, scale);
            bx_[q][1] = __fmul_rn(tly, scale);
            bx_[q][2] = __fmul_rn(brx, scale);
            bx_[q][3] = __fmul_rn(bry, scale);
        }
    }
    int mysum = f_[0] + f_[1];

    // wave-level inclusive scan
    int x = mysum;
#pragma unroll
    for (int off = 1; off < 64; off <<= 1) {
        int y = __shfl_up(x, off, 64);
        if (lane >= off) x += y;
    }
    if (lane == 63) wsum[wid] = x;
    __syncthreads();
    if (wid == 0 && lane < 16) {
        int s = wsum[lane];
#pragma unroll
        for (int off = 1; off < 16; off <<= 1) {
            int y = __shfl_up(s, off, 64);
            if (lane >= off) s += y;
        }
        wsum[lane] = s;
    }
    __syncthreads();
    int wave_off = (wid > 0) ? wsum[wid - 1] : 0;
    int V = wsum[15];
    int base_excl = (x + wave_off) - mysum;

    float* dbase = det + ((size_t)b * 3000 + (size_t)l * 1000) * 7;
#pragma unroll
    for (int q = 0; q < 2; q++) {
        int k = 2 * tid + q;
        if (k < K) {
            int pos = base_excl + (q == 1 ? f_[0] : 0);
            int rank = f_[q] ? pos : V + (k - pos);
            if (rank < 1000 && rank != 6) {
                float* drow = dbase + (size_t)rank * 7;
                drow[0] = s_[q];
                drow[1] = bx_[q][0];
                drow[2] = bx_[q][1];
                drow[3] = bx_[q][2];
                drow[4] = bx_[q][3];
                drow[5] = 0.f;
                drow[6] = 0.f;
            }
        }
    }
    if (tid == 0) {
        float lv = (float)l;
        float* drow = dbase + 6 * 7;
#pragma unroll
        for (int j = 0; j < 7; j++) drow[j] = lv;
    }
}

// ---------------- final: merge-rank of 3 sorted lists (+3 clobbered singletons) ----------------
__device__ __forceinline__ bool key_gt(float sa, int ga, float sb, int gb) {
    return (sa > sb) || (sa == sb && ga < gb);
}

__global__ __launch_bounds__(1024) void final_kernel(const float* __restrict__ det,
                                                     float* __restrict__ out)
{
    int b = blockIdx.x;
    __shared__ float sc[3000];
    int tid = threadIdx.x;
    const float* dbase = det + (size_t)b * 3000 * 7;
    for (int i = tid; i < 3000; i += 1024) sc[i] = dbase[(size_t)i * 7];
    __syncthreads();

    for (int e = tid; e < 3000; e += 1024) {
        float se = sc[e];
        int ge = e;
        int rank = 0;
#pragma unroll
        for (int lp = 0; lp < 3; lp++) {
            int lo = 0, hiB = 999;
            while (lo < hiB) {
                int mid = (lo + hiB) >> 1;
                int p = mid + (mid >= 6 ? 1 : 0);
                int g = lp * 1000 + p;
                if (key_gt(sc[g], g, se, ge)) lo = mid + 1; else hiB = mid;
            }
            rank += lo;
        }
#pragma unroll
        for (int ls = 0; ls < 3; ls++) {
            int g = ls * 1000 + 6;
            if (g != e && key_gt((float)ls, g, se, ge)) rank++;
        }
        if (rank < 1000) {
            const float* src = dbase + (size_t)e * 7;
            float* dst = out + ((size_t)b * 1000 + rank) * 7;
#pragma unroll
            for (int j = 0; j < 7; j++) dst[j] = src[j];
        }
    }
}

extern "C" void kernel_launch(void* const* d_in, const int* in_sizes, int n_in,
                              void* d_out, int out_size, void* d_ws, size_t ws_size,
                              hipStream_t stream)
{
    (void)in_sizes; (void)n_in; (void)out_size; (void)ws_size;
    const float* h0 = (const float*)d_in[0];
    const float* t0 = (const float*)d_in[1];
    const float* r0 = (const float*)d_in[2];
    const float* h1 = (const float*)d_in[3];
    const float* t1 = (const float*)d_in[4];
    const float* r1 = (const float*)d_in[5];
    const float* h2 = (const float*)d_in[6];
    const float* t2 = (const float*)d_in[7];
    const float* r2 = (const float*)d_in[8];
    float* out = (float*)d_out;

    // Workspace layout (bytes):
    //   pbc  : 848*4       = 3392      @ 0
    //   loose: 335872*8    = 2686976   @ 3392     (8B aligned)
    //   cand : 48*4096*8   = 1572864   @ 2690368  (8B aligned)
    //   det  : 16*3000*7*4 = 1344000   @ 4263232
    char* ws = (char*)d_ws;
    int* pbc  = (int*)ws;
    unsigned long long* loose = (unsigned long long*)(ws + 3392);
    unsigned long long* cand  = (unsigned long long*)(ws + 2690368);
    float* det = (float*)(ws + 4263232);

    collect_kernel<<<dim3(40, 16, 3), 256, 0, stream>>>(h0, h1, h2, pbc, loose);
    sort_kernel<<<48, 256, 0, stream>>>(h0, h1, h2, pbc, loose, cand);
    build_kernel<<<48, 1024, 0, stream>>>(t0, t1, t2, r0, r1, r2, cand, det);
    final_kernel<<<16, 1024, 0, stream>>>(det, out);
}